// Round 15
// baseline (185.447 us; speedup 1.0000x reference)
//
#include <hip/hip_runtime.h>
#include <math.h>

// NNCLR forward loss. fp16 MFMA GEMMs, deterministic fp32 rescore, fixed-shift
// LSE. k_nn: 512-thread block, 3-buffer LDS rotation, counted vmcnt(4) +
// single s_barrier per 128-row step (no vmcnt(0) drain in steady state).
// prep -> k_nn(+atomic rowmax) -> rescore -> gather -> loss -> merge

#define B_N 4096
#define D_N 128
#define NP 8192    // 2*B p-rows
#define NTILE 512  // 64-wide q tiles
#define INV_T 10.0f
#define C1F (10.0f * 1.4426950408889634f)
#define C2F (16.0f * 1.4426950408889634f)
#define W_WIN 8e-3f  // > 2*(fp16 sim err ~2.5e-3) + ulp: deterministic cover

typedef _Float16 half8 __attribute__((ext_vector_type(8)));
typedef __fp16 fp16x2 __attribute__((ext_vector_type(2)));
typedef float f32x4 __attribute__((ext_vector_type(4)));
union H8 { half8 v; fp16x2 h2[4]; };

// ws byte offsets (total ~21 MB; harness provides 256 MB)
#define OFF_PH 0u          // 2 MB   normalized p fp16 [8192][128]
#define OFF_QH 2097152u    // 8 MB   fp16 queue [32768][128]
#define OFF_NH 10485760u   // 2 MB   fp16 neighbours [8192][128]
#define OFF_TV 12582912u   // 8 MB   [512][8192] fp16 tile maxes
#define OFF_RMU 20971520u  // 32 KB  [8192] u32 packed row maxes (atomic)
#define OFF_KEY 21004288u  // 64 KB
#define OFF_DG 21069824u   // 32 KB
#define OFF_SP 21102592u   // 256 KB [16384][4] row-LSE partials

#define VMCNT(N) asm volatile("s_waitcnt vmcnt(" #N ")" ::: "memory")

__device__ __forceinline__ void gload16(const void* g, void* l) {
  __builtin_amdgcn_global_load_lds((const __attribute__((address_space(1))) void*)g,
                                   (__attribute__((address_space(3))) void*)l, 16, 0, 0);
}

__device__ __forceinline__ unsigned packf(float f) {
  unsigned u = __float_as_uint(f);
  return ((int)u < 0) ? ~u : (u | 0x80000000u);
}
__device__ __forceinline__ float unpackf(unsigned p) {
  unsigned v = (p & 0x80000000u) ? (p & 0x7fffffffu) : ~p;
  return __uint_as_float(v);
}

// ---- fused prep: blocks 0..2047 convert queue to fp16; 2048..4095 normalize p
//      rows to fp16 and init keys/rmu ----
__global__ __launch_bounds__(256) void k_prep(const float* __restrict__ in1,
                                              const float* __restrict__ in2,
                                              const float* __restrict__ queue,
                                              _Float16* __restrict__ Ph,
                                              _Float16* __restrict__ Qh,
                                              unsigned long long* __restrict__ keys,
                                              unsigned* __restrict__ rmu) {
  int bid = blockIdx.x, t = threadIdx.x;
  if (bid < 2048) {  // qcvt: half8 groups
    int i = bid * 256 + t;
    const float* s = queue + (size_t)i * 8;
    float4 x = *(const float4*)s;
    float4 y = *(const float4*)(s + 4);
    H8 h;
    h.h2[0] = __builtin_amdgcn_cvt_pkrtz(x.x, x.y);
    h.h2[1] = __builtin_amdgcn_cvt_pkrtz(x.z, x.w);
    h.h2[2] = __builtin_amdgcn_cvt_pkrtz(y.x, y.y);
    h.h2[3] = __builtin_amdgcn_cvt_pkrtz(y.z, y.w);
    *(half8*)(Qh + (size_t)i * 8) = h.v;
  } else {
    int w = t >> 6, l = t & 63;
    int g = (bid - 2048) * 4 + w;  // 0..8191
    int view = g >> 12, row = g & (B_N - 1);
    const float* src = (view ? in2 : in1) + (size_t)row * D_N;
    float2 v = *(const float2*)(src + 2 * l);
    float ss = fmaf(v.x, v.x, v.y * v.y);
#pragma unroll
    for (int m = 1; m < 64; m <<= 1) ss += __shfl_xor(ss, m);
    float rn = 1.0f / sqrtf(ss);
    *(fp16x2*)(Ph + (size_t)g * D_N + 2 * l) = __builtin_amdgcn_cvt_pkrtz(v.x * rn, v.y * rn);
    if (l == 0) keys[g] = 0ull;
    if (l == 1) rmu[g] = 0u;
  }
}

// Stage 128 rows x 256 B with 256 threads (4 waves): 8 gload16/thread.
#define STAGE128(MAT, RB, BUF)                                                 \
  {                                                                            \
    _Pragma("unroll") for (int j = 0; j < 8; ++j) {                            \
      int ch = w * 8 + j;                                                      \
      int r = (ch << 2) + l4;                                                  \
      gload16(MAT + (((RB) + r) << 7) + ((l15 ^ (r & 7)) << 3),                \
              (char*)(&sm[BUF][0]) + (ch << 10));                              \
    }                                                                          \
  }

// Stage 128 rows x 256 B with 512 threads (8 waves): 4 gload16/thread.
#define STAGE128W8(MAT, RB, BUF)                                               \
  {                                                                            \
    _Pragma("unroll") for (int j = 0; j < 4; ++j) {                            \
      int ch = w * 4 + j;                                                      \
      int r = (ch << 2) + l4;                                                  \
      gload16(MAT + (((RB) + r) << 7) + ((l15 ^ (r & 7)) << 3),                \
              (char*)(&sm[BUF][0]) + (ch << 10));                              \
    }                                                                          \
  }

// ---- NN screen: 128p x 2048q per 512-thread block; 128-q-row steps over a
//      3-buffer rotation; waves: wq = w&1 (64-q half), wp = w>>1 (32-p... no:
//      wp in 0..3 picks 32-col group? No -- wp picks one of 4 64-col groups of
//      the 128 p-cols x 2 q-halves: 8 waves = 2q x 4p?? p is 128 wide -> wp
//      in 0..1 would suffice; we use 2q x 2p x 2 duplicate-free split:
//      Actually: 8 waves = wq (2 q-halves) x wp (2 p-halves) x ws (2 q-subhalves).
//      Simpler: wq2 = w&3 picks 32-q-row quarter, wp = w>>2 picks 64-p half.
//      Per wave: 2 ti x 4 tj x 4 ks = 32 MFMA ... -- NO. Keep per-wave economics
//      equal to r8: wave handles 64 q-rows x 64 p-cols (4x4 tiles, 64 MFMA):
//      8 waves cover 128q x 128p exactly (wq = w&1 -> 64-q half, wp = w>>1 &1
//      -> 64-p half, wd = w>>2 -> 64-row step-half... that's 2x2x2 = 8 over a
//      128x128 output with each wave doing a DISTINCT 64x64 quadrant twice??
//      128x128 output = 4 quadrants; 8 waves -> each quadrant computed by 2
//      waves. To keep all 8 busy distinctly, each block instead covers
//      128 p-cols x 2048 q with STEP = 256 q-rows? LDS 3x64KB = 192 > 160.
//      Resolution: block covers 128p x 2048q, step = 128 q-rows, and the 8
//      waves split as wq in 0..3 (32-q quarter) x wp in 0..1 (64-p half):
//      per wave 2 ti x 4 tj x 4 ks = 32 MFMA, 8 ds_read, 8 Pf4 frags.
//      Same barrier cadence, half the per-wave MFMA of r8 but same per-CU
//      totals; the counted-vmcnt removes the drain that made r9's small
//      clusters lose. tv tile = 64 q rows = 2 wq quarters -> combine via LDS?
//      No: tv granularity stays 64-q tiles; the two wq quarters of a tile are
//      in different waves -> use 32-row tv tiles?? TV layout is [512][8192]
//      64-row tiles. Combine instead IN-REGISTER: each wave's 32-row max ->
//      cross-wave combine via small LDS smax buffer double-buffered, written
//      after MFMA, read next step (one extra barrier... NO).
//      FINAL CHOICE: keep per-wave tile ownership: wq in 0..1 owns the FULL
//      64-q tile rows via ti in 0..3 over its half? -- identical to r8 with
//      8 waves meaning each 64x64 quadrant done by waves {w, w+4} both?? 
//      Simplest correct: wq = w&1, wp = (w>>1)&1, dup = w>>2; quadrant work
//      split along ks: dup=0 does ks 0,1; dup=1 does ks 2,3 -> partial sums
//      combined via... requires cross-wave add. TOO COMPLEX.
// ==> Use 256-thread blocks (4 waves, r8-identical wave split) with the
//     3-buffer counted-vmcnt rotation; 2 blocks/CU needs 192 KB -> exceeds
//     160, so run 1 block/CU (1024 blocks, 4 sequential rounds/CU). The
//     counted vmcnt makes intra-block overlap replace the lost 2nd block.
__global__ __launch_bounds__(256, 2) void k_nn(const _Float16* __restrict__ Qh,
                                               const _Float16* __restrict__ Ph,
                                               _Float16* __restrict__ tv,
                                               unsigned* __restrict__ rmu) {
  __shared__ _Float16 sm[3][16384];  // 3 x 32 KB rotation (96 KB -> 1 block/CU)
  int bid = blockIdx.x;
  int qc = (bid & 7) | ((bid >> 9) << 3);  // chunks 0-7 first, then 8-15
  int pb = (bid >> 3) & 63;
  int t = threadIdx.x, l = t & 63, w = t >> 6;
  int wq = w >> 1, wp = w & 1, l15 = l & 15, l4 = l >> 4;
  // stationary P fragments (B-operand): col = l15, k = l4*8 + i
  half8 Pf4[4][4];
  const _Float16* pbase = Ph + (size_t)(pb * 128 + wp * 64 + l15) * D_N + l4 * 8;
#pragma unroll
  for (int tj = 0; tj < 4; ++tj)
#pragma unroll
    for (int ks = 0; ks < 4; ++ks)
      Pf4[tj][ks] = *(const half8*)(pbase + (size_t)tj * 16 * D_N + ks * 32);
  const size_t qrow0 = (size_t)qc * 2048;
  int tidb = qc * 32;
  int pcol = pb * 128 + wp * 64 + l15;
  float runm[4];
#pragma unroll
  for (int tj = 0; tj < 4; ++tj) runm[tj] = -3e38f;
  STAGE128(Qh, qrow0, 0)
  STAGE128(Qh, qrow0 + 128, 1)
#pragma unroll 1
  for (int qt = 0; qt < 16; ++qt) {
    int cur = qt % 3;
    // stage(qt) issued 2 iters ago; stage(qt+1) (8 loads/thread) still in
    // flight -> wait depth 8, not 0. Last iter: nothing younger -> drain.
    if (qt < 15) {
      VMCNT(8);
    } else {
      VMCNT(0);
    }
    __builtin_amdgcn_s_barrier();
    __builtin_amdgcn_sched_barrier(0);
    if (qt + 2 < 16) STAGE128(Qh, qrow0 + (size_t)(qt + 2) * 128, (qt + 2) % 3)
    const char* bb = (const char*)(&sm[cur][0]);
    f32x4 acc[4][4];
#pragma unroll
    for (int i = 0; i < 4; ++i)
#pragma unroll
      for (int j = 0; j < 4; ++j) acc[i][j] = (f32x4){0.f, 0.f, 0.f, 0.f};
#pragma unroll
    for (int ks = 0; ks < 4; ++ks) {
      half8 Qf[4];
#pragma unroll
      for (int ti = 0; ti < 4; ++ti) {
        int qloc = wq * 64 + ti * 16 + l15;
        int byteo = qloc * 256 + ((((ks << 2) + l4) ^ (qloc & 7)) << 4);
        Qf[ti] = *(const half8*)(bb + byteo);
      }
#pragma unroll
      for (int ti = 0; ti < 4; ++ti)
#pragma unroll
        for (int tj = 0; tj < 4; ++tj)
          acc[ti][tj] =
              __builtin_amdgcn_mfma_f32_16x16x32_f16(Qf[ti], Pf4[tj][ks], acc[ti][tj], 0, 0, 0);
    }
    int tid = tidb + qt * 2 + wq;
#pragma unroll
    for (int tj = 0; tj < 4; ++tj) {
      float m = acc[0][tj][0];
#pragma unroll
      for (int ti = 0; ti < 4; ++ti)
#pragma unroll
        for (int r = 0; r < 4; ++r) m = fmaxf(m, acc[ti][tj][r]);
      m = fmaxf(m, __shfl_xor(m, 16));
      m = fmaxf(m, __shfl_xor(m, 32));
      runm[tj] = fmaxf(runm[tj], m);
      if (l4 == 0) tv[(size_t)tid * NP + pcol + tj * 16] = (_Float16)m;
    }
  }
  if (l4 == 0) {
#pragma unroll
    for (int tj = 0; tj < 4; ++tj) atomicMax(rmu + pcol + tj * 16, packf(runm[tj]));
  }
}

// ---- exact fp32 rescore, 2 blocks/tile (32 q-rows each): vectorized scan of
//      own TV column vs unpacked rmu -> cand LDS -> 8 candidates in flight ----
__global__ __launch_bounds__(256) void k_rescore(const float* __restrict__ queue,
                                                 const float* __restrict__ in1,
                                                 const float* __restrict__ in2,
                                                 const _Float16* __restrict__ tv,
                                                 const unsigned* __restrict__ rmu,
                                                 unsigned long long* __restrict__ keys) {
  __shared__ float Qs[32][132];
  __shared__ unsigned short cand[NP];
  __shared__ int cnt;
  int tile = blockIdx.x, qh = blockIdx.y, t = threadIdx.x;
  if (t == 0) cnt = 0;
  __syncthreads();
  int qbase = tile * 64 + qh * 32;
#pragma unroll
  for (int j = 0; j < 4; ++j) {
    int i = j * 256 + t;  // 0..1023 float4s
    int r = i >> 5, c = i & 31;
    *(float4*)(&Qs[r][c << 2]) = *(const float4*)(queue + ((size_t)(qbase + r) << 7) + (c << 2));
  }
  const _Float16* tvrow = tv + (size_t)tile * NP;
#pragma unroll
  for (int j = 0; j < 4; ++j) {
    int p0 = j * 2048 + t * 8;
    half8 tvv = *(const half8*)(tvrow + p0);
    uint4 u0 = *(const uint4*)(rmu + p0);
    uint4 u1 = *(const uint4*)(rmu + p0 + 4);
    unsigned uu[8] = {u0.x, u0.y, u0.z, u0.w, u1.x, u1.y, u1.z, u1.w};
#pragma unroll
    for (int k = 0; k < 8; ++k) {
      if ((float)tvv[k] >= unpackf(uu[k]) - W_WIN) {
        int pos = atomicAdd(&cnt, 1);
        cand[pos] = (unsigned short)(p0 + k);
      }
    }
  }
  __syncthreads();
  int n = cnt;
  int w = t >> 6, l = t & 63, hl = l >> 5, ll = l & 31;
  for (int ci = w * 2 + hl; ci < n; ci += 8) {
    int p = cand[ci];
    const float* prow = (p < B_N) ? (in1 + ((size_t)p << 7)) : (in2 + ((size_t)(p - B_N) << 7));
    float d = 0.f;
#pragma unroll
    for (int k = 0; k < 32; ++k) {
      float4 a = *(const float4*)(prow + (k << 2));
      float4 b = *(const float4*)(&Qs[ll][k << 2]);
      d = fmaf(a.x, b.x, d);
      d = fmaf(a.y, b.y, d);
      d = fmaf(a.z, b.z, d);
      d = fmaf(a.w, b.w, d);
    }
    int idx = qbase + ll;
#pragma unroll
    for (int m = 1; m < 32; m <<= 1) {
      float ov = __shfl_xor(d, m);
      int oi = __shfl_xor(idx, m);
      if (ov > d || (ov == d && oi < idx)) {
        d = ov;
        idx = oi;
      }
    }
    if (ll == 0) {
      unsigned long long key = ((unsigned long long)packf(d) << 32) | (unsigned)(~idx);
      atomicMax(keys + p, key);
    }
  }
}

// ---- gather: Nh = fp16(queue[idx]); diag = dot(nn, p_other) exact fp32 ----
__global__ __launch_bounds__(256) void k_gather(const float* __restrict__ queue,
                                                const float* __restrict__ in1,
                                                const float* __restrict__ in2,
                                                const unsigned long long* __restrict__ keys,
                                                _Float16* __restrict__ Nh,
                                                float* __restrict__ diag) {
  int t = threadIdx.x, w = t >> 6, l = t & 63;
  int g = blockIdx.x * 4 + w;  // 0..8191
  int view = g >> 12, row = g & (B_N - 1);
  unsigned long long key = keys[g];
  int qidx = (int)(~(unsigned)(key & 0xffffffffull));
  const float* q = queue + (size_t)qidx * D_N;
  float2 qv = *(const float2*)(q + 2 * l);
  *(fp16x2*)(Nh + (size_t)g * D_N + 2 * l) = __builtin_amdgcn_cvt_pkrtz(qv.x, qv.y);
  const float* oth = (view ? in1 : in2) + (size_t)row * D_N;
  float2 ov = *(const float2*)(oth + 2 * l);
  float ss = fmaf(ov.x, ov.x, ov.y * ov.y);
  float d = fmaf(qv.x, ov.x, qv.y * ov.y);
#pragma unroll
  for (int m = 1; m < 64; m <<= 1) {
    ss += __shfl_xor(ss, m);
    d += __shfl_xor(d, m);
  }
  if (l == 0) diag[g] = d / sqrtf(ss);
}

// ---- loss GEMM: 2x2 waves, 128 A-rows x 128 B-cols per block, B staged
//      (dbuf + swizzle); fixed-shift LSE partials over 1024-col chunks ----
__global__ __launch_bounds__(256, 2) void k_loss(const _Float16* __restrict__ Ph,
                                                 const _Float16* __restrict__ Nh,
                                                 float* __restrict__ Spart) {
  __shared__ _Float16 sm[2][16384];
  __shared__ float sred[2][2][64];
  int rb = blockIdx.x;     // 0..127
  int chunk = blockIdx.y;  // 0..3
  int pair = rb >> 5, rowblk = rb & 31;
  const size_t BDh = (size_t)B_N * D_N;
  const _Float16* A = (pair == 0) ? Nh : (pair == 1) ? (Ph + BDh) : (pair == 2) ? (Nh + BDh) : Ph;
  const _Float16* Bm = (pair == 0) ? (Ph + BDh) : (pair == 1) ? Nh : (pair == 2) ? Ph : (Nh + BDh);
  int t = threadIdx.x, l = t & 63, w = t >> 6;
  int wr = w >> 1, wc = w & 1, l15 = l & 15, l4 = l >> 4;
  half8 Af[4][4];
  const _Float16* ab = A + (size_t)(rowblk * 128 + wr * 64 + l15) * D_N + l4 * 8;
#pragma unroll
  for (int ti = 0; ti < 4; ++ti)
#pragma unroll
    for (int ks = 0; ks < 4; ++ks)
      Af[ti][ks] = *(const half8*)(ab + (size_t)ti * 16 * D_N + ks * 32);
  float S[16];
#pragma unroll
  for (int i = 0; i < 16; ++i) S[i] = 0.f;
  const size_t crow0 = (size_t)chunk * 1024;
  STAGE128(Bm, crow0, 0)
#pragma unroll 1
  for (int ct = 0; ct < 8; ++ct) {
    int cur = ct & 1;
    __syncthreads();
    if (ct < 7) STAGE128(Bm, crow0 + (ct + 1) * 128, cur ^ 1)
    const char* bbp = (const char*)(&sm[cur][0]);
    f32x4 acc[4][4];
#pragma unroll
    for (int i = 0; i < 4; ++i)
#pragma unroll
      for (int j = 0; j < 4; ++j) acc[i][j] = (f32x4){0.f, 0.f, 0.f, 0.f};
#pragma unroll
    for (int ks = 0; ks < 4; ++ks) {
      half8 Bf[4];
#pragma unroll
      for (int tj = 0; tj < 4; ++tj) {
        int bloc = wc * 64 + tj * 16 + l15;
        int byteo = bloc * 256 + ((((ks << 2) + l4) ^ (bloc & 7)) << 4);
        Bf[tj] = *(const half8*)(bbp + byteo);
      }
#pragma unroll
      for (int ti = 0; ti < 4; ++ti)
#pragma unroll
        for (int tj = 0; tj < 4; ++tj)
          acc[ti][tj] =
              __builtin_amdgcn_mfma_f32_16x16x32_f16(Af[ti][ks], Bf[tj], acc[ti][tj], 0, 0, 0);
    }
#pragma unroll
    for (int ti = 0; ti < 4; ++ti)
#pragma unroll
      for (int r = 0; r < 4; ++r) {
        float e = 0.f;
#pragma unroll
        for (int tj = 0; tj < 4; ++tj) e += exp2f(fmaf(acc[ti][tj][r], C1F, -C2F));
        S[ti * 4 + r] += e;
      }
  }
#pragma unroll
  for (int i = 0; i < 16; ++i) {
#pragma unroll
    for (int m = 1; m < 16; m <<= 1) S[i] += __shfl_xor(S[i], m);
  }
  __syncthreads();
  if (l15 == 0) {
#pragma unroll
    for (int ti = 0; ti < 4; ++ti)
#pragma unroll
      for (int r = 0; r < 4; ++r) sred[wr][wc][ti * 16 + l4 * 4 + r] = S[ti * 4 + r];
  }
  __syncthreads();
  if (t < 128) {
    int wrr = t >> 6, rl = t & 63;
    float s = sred[wrr][0][rl] + sred[wrr][1][rl];
    int row = pair * B_N + rowblk * 128 + wrr * 64 + rl;
    Spart[(size_t)row * 4 + chunk] = s;
  }
}

__global__ __launch_bounds__(256) void k_merge(const float* __restrict__ Spart,
                                               const float* __restrict__ diag,
                                               float* __restrict__ out) {
  int row = blockIdx.x * 256 + threadIdx.x;  // 0..16383
  const float* sp = Spart + (size_t)row * 4;
  float s = sp[0] + sp[1] + sp[2] + sp[3];
  int pair = row >> 12, r = row & (B_N - 1);
  float dg = diag[(pair >> 1) * B_N + r];
  out[row] = logf(s) + 16.0f - INV_T * dg;
}

extern "C" void kernel_launch(void* const* d_in, const int* in_sizes, int n_in,
                              void* d_out, int out_size, void* d_ws, size_t ws_size,
                              hipStream_t stream) {
  const float* in1 = (const float*)d_in[0];
  const float* in2 = (const float*)d_in[1];
  const float* queue = (const float*)d_in[2];
  float* out = (float*)d_out;
  char* ws = (char*)d_ws;
  _Float16* Ph = (_Float16*)(ws + OFF_PH);
  _Float16* Qhh = (_Float16*)(ws + OFF_QH);
  _Float16* Nh = (_Float16*)(ws + OFF_NH);
  _Float16* TV = (_Float16*)(ws + OFF_TV);
  unsigned* RMU = (unsigned*)(ws + OFF_RMU);
  unsigned long long* KEY = (unsigned long long*)(ws + OFF_KEY);
  float* DG = (float*)(ws + OFF_DG);
  float* SP = (float*)(ws + OFF_SP);

  hipLaunchKernelGGL(k_prep, dim3(4096), dim3(256), 0, stream, in1, in2, queue, Ph, Qhh, KEY, RMU);
  hipLaunchKernelGGL(k_nn, dim3(1024), dim3(256), 0, stream, Qhh, Ph, TV, RMU);
  hipLaunchKernelGGL(k_rescore, dim3(512, 2), dim3(256), 0, stream, queue, in1, in2, TV, RMU, KEY);
  hipLaunchKernelGGL(k_gather, dim3(2048), dim3(256), 0, stream, queue, in1, in2, KEY, Nh, DG);
  hipLaunchKernelGGL(k_loss, dim3(128, 4), dim3(256), 0, stream, Ph, Nh, SP);
  hipLaunchKernelGGL(k_merge, dim3(64), dim3(256), 0, stream, SP, DG, out);
}

// Round 16
// 144.240 us; speedup vs baseline: 1.2857x; 1.2857x over previous
//
#include <hip/hip_runtime.h>
#include <math.h>

// NNCLR forward loss. fp16 MFMA GEMMs (proven 2x2-wave, 128-row staged dbuf
// structure at its ~910 TF structural ceiling), deterministic fp32 rescore,
// fixed-shift LSE. 6-kernel chain (round-11 configuration, best measured):
// prep(norm+qcvt+inits) -> k_nn(+atomic rowmax) -> rescore(scan+dots) ->
// gather -> loss -> merge

#define B_N 4096
#define D_N 128
#define NP 8192    // 2*B p-rows
#define NTILE 512  // 64-wide q tiles
#define INV_T 10.0f
#define C1F (10.0f * 1.4426950408889634f)
#define C2F (16.0f * 1.4426950408889634f)
#define W_WIN 8e-3f  // > 2*(fp16 sim err ~2.5e-3) + ulp: deterministic cover

typedef _Float16 half8 __attribute__((ext_vector_type(8)));
typedef __fp16 fp16x2 __attribute__((ext_vector_type(2)));
typedef float f32x4 __attribute__((ext_vector_type(4)));
union H8 { half8 v; fp16x2 h2[4]; };

// ws byte offsets (total ~21 MB; harness provides 256 MB)
#define OFF_PH 0u          // 2 MB   normalized p fp16 [8192][128]
#define OFF_QH 2097152u    // 8 MB   fp16 queue [32768][128]
#define OFF_NH 10485760u   // 2 MB   fp16 neighbours [8192][128]
#define OFF_TV 12582912u   // 8 MB   [512][8192] fp16 tile maxes
#define OFF_RMU 20971520u  // 32 KB  [8192] u32 packed row maxes (atomic)
#define OFF_KEY 21004288u  // 64 KB
#define OFF_DG 21069824u   // 32 KB
#define OFF_SP 21102592u   // 256 KB [16384][4] row-LSE partials

__device__ __forceinline__ void gload16(const void* g, void* l) {
  __builtin_amdgcn_global_load_lds((const __attribute__((address_space(1))) void*)g,
                                   (__attribute__((address_space(3))) void*)l, 16, 0, 0);
}

__device__ __forceinline__ unsigned packf(float f) {
  unsigned u = __float_as_uint(f);
  return ((int)u < 0) ? ~u : (u | 0x80000000u);
}
__device__ __forceinline__ float unpackf(unsigned p) {
  unsigned v = (p & 0x80000000u) ? (p & 0x7fffffffu) : ~p;
  return __uint_as_float(v);
}

// ---- fused prep: blocks 0..2047 convert queue to fp16; 2048..4095 normalize p
//      rows to fp16 and init keys/rmu ----
__global__ __launch_bounds__(256) void k_prep(const float* __restrict__ in1,
                                              const float* __restrict__ in2,
                                              const float* __restrict__ queue,
                                              _Float16* __restrict__ Ph,
                                              _Float16* __restrict__ Qh,
                                              unsigned long long* __restrict__ keys,
                                              unsigned* __restrict__ rmu) {
  int bid = blockIdx.x, t = threadIdx.x;
  if (bid < 2048) {  // qcvt: half8 groups
    int i = bid * 256 + t;
    const float* s = queue + (size_t)i * 8;
    float4 x = *(const float4*)s;
    float4 y = *(const float4*)(s + 4);
    H8 h;
    h.h2[0] = __builtin_amdgcn_cvt_pkrtz(x.x, x.y);
    h.h2[1] = __builtin_amdgcn_cvt_pkrtz(x.z, x.w);
    h.h2[2] = __builtin_amdgcn_cvt_pkrtz(y.x, y.y);
    h.h2[3] = __builtin_amdgcn_cvt_pkrtz(y.z, y.w);
    *(half8*)(Qh + (size_t)i * 8) = h.v;
  } else {
    int w = t >> 6, l = t & 63;
    int g = (bid - 2048) * 4 + w;  // 0..8191
    int view = g >> 12, row = g & (B_N - 1);
    const float* src = (view ? in2 : in1) + (size_t)row * D_N;
    float2 v = *(const float2*)(src + 2 * l);
    float ss = fmaf(v.x, v.x, v.y * v.y);
#pragma unroll
    for (int m = 1; m < 64; m <<= 1) ss += __shfl_xor(ss, m);
    float rn = 1.0f / sqrtf(ss);
    *(fp16x2*)(Ph + (size_t)g * D_N + 2 * l) = __builtin_amdgcn_cvt_pkrtz(v.x * rn, v.y * rn);
    if (l == 0) keys[g] = 0ull;
    if (l == 1) rmu[g] = 0u;
  }
}

// Stage 128 rows x 256 B into sm[BUF]: thread issues 8 gload16 (ch = w*8+j,
// 1 KB per ch). LDS linear dest; global source pre-swizzled (slot l15^(r&7)).
#define STAGE128(MAT, RB, BUF)                                                 \
  {                                                                            \
    _Pragma("unroll") for (int j = 0; j < 8; ++j) {                            \
      int ch = w * 8 + j;                                                      \
      int r = (ch << 2) + l4;                                                  \
      gload16(MAT + (((RB) + r) << 7) + ((l15 ^ (r & 7)) << 3),                \
              (char*)(&sm[BUF][0]) + (ch << 10));                              \
    }                                                                          \
  }

// ---- NN screen: 128p x 2048q per block; 128-q-row dbuf steps; 2x2 wave split
//      (wq picks 64 q-rows, wp picks 64 p-cols); per-64q-tile max via shfl;
//      per-row global max via one packed atomicMax per column at the end. ----
__global__ __launch_bounds__(256, 2) void k_nn(const _Float16* __restrict__ Qh,
                                               const _Float16* __restrict__ Ph,
                                               _Float16* __restrict__ tv,
                                               unsigned* __restrict__ rmu) {
  __shared__ _Float16 sm[2][16384];  // 2 x 32 KB (128 q-rows x 128 d fp16)
  int bid = blockIdx.x;
  int qc = (bid & 7) | ((bid >> 9) << 3);  // chunks 0-7 first, then 8-15
  int pb = (bid >> 3) & 63;
  int t = threadIdx.x, l = t & 63, w = t >> 6;
  int wq = w >> 1, wp = w & 1, l15 = l & 15, l4 = l >> 4;
  // stationary P fragments (B-operand): col = l15, k = l4*8 + i
  half8 Pf4[4][4];
  const _Float16* pbase = Ph + (size_t)(pb * 128 + wp * 64 + l15) * D_N + l4 * 8;
#pragma unroll
  for (int tj = 0; tj < 4; ++tj)
#pragma unroll
    for (int ks = 0; ks < 4; ++ks)
      Pf4[tj][ks] = *(const half8*)(pbase + (size_t)tj * 16 * D_N + ks * 32);
  const size_t qrow0 = (size_t)qc * 2048;
  int tidb = qc * 32;
  int pcol = pb * 128 + wp * 64 + l15;
  float runm[4];
#pragma unroll
  for (int tj = 0; tj < 4; ++tj) runm[tj] = -3e38f;
  STAGE128(Qh, qrow0, 0)
#pragma unroll 1
  for (int qt = 0; qt < 16; ++qt) {
    int cur = qt & 1;
    __syncthreads();
    if (qt < 15) STAGE128(Qh, qrow0 + (qt + 1) * 128, cur ^ 1)
    const char* bb = (const char*)(&sm[cur][0]);
    f32x4 acc[4][4];
#pragma unroll
    for (int i = 0; i < 4; ++i)
#pragma unroll
      for (int j = 0; j < 4; ++j) acc[i][j] = (f32x4){0.f, 0.f, 0.f, 0.f};
#pragma unroll
    for (int ks = 0; ks < 4; ++ks) {
      half8 Qf[4];
#pragma unroll
      for (int ti = 0; ti < 4; ++ti) {
        int qloc = wq * 64 + ti * 16 + l15;
        int byteo = qloc * 256 + ((((ks << 2) + l4) ^ (qloc & 7)) << 4);
        Qf[ti] = *(const half8*)(bb + byteo);
      }
#pragma unroll
      for (int ti = 0; ti < 4; ++ti)
#pragma unroll
        for (int tj = 0; tj < 4; ++tj)
          acc[ti][tj] =
              __builtin_amdgcn_mfma_f32_16x16x32_f16(Qf[ti], Pf4[tj][ks], acc[ti][tj], 0, 0, 0);
    }
    int tid = tidb + qt * 2 + wq;
#pragma unroll
    for (int tj = 0; tj < 4; ++tj) {
      float m = acc[0][tj][0];
#pragma unroll
      for (int ti = 0; ti < 4; ++ti)
#pragma unroll
        for (int r = 0; r < 4; ++r) m = fmaxf(m, acc[ti][tj][r]);
      m = fmaxf(m, __shfl_xor(m, 16));
      m = fmaxf(m, __shfl_xor(m, 32));
      runm[tj] = fmaxf(runm[tj], m);
      if (l4 == 0) tv[(size_t)tid * NP + pcol + tj * 16] = (_Float16)m;
    }
  }
  if (l4 == 0) {
#pragma unroll
    for (int tj = 0; tj < 4; ++tj) atomicMax(rmu + pcol + tj * 16, packf(runm[tj]));
  }
}

// ---- exact fp32 rescore, 2 blocks/tile (32 q-rows each): vectorized scan of
//      own TV column vs unpacked rmu -> cand LDS -> 8 candidates in flight ----
__global__ __launch_bounds__(256) void k_rescore(const float* __restrict__ queue,
                                                 const float* __restrict__ in1,
                                                 const float* __restrict__ in2,
                                                 const _Float16* __restrict__ tv,
                                                 const unsigned* __restrict__ rmu,
                                                 unsigned long long* __restrict__ keys) {
  __shared__ float Qs[32][132];
  __shared__ unsigned short cand[NP];
  __shared__ int cnt;
  int tile = blockIdx.x, qh = blockIdx.y, t = threadIdx.x;
  if (t == 0) cnt = 0;
  __syncthreads();
  int qbase = tile * 64 + qh * 32;
#pragma unroll
  for (int j = 0; j < 4; ++j) {
    int i = j * 256 + t;  // 0..1023 float4s
    int r = i >> 5, c = i & 31;
    *(float4*)(&Qs[r][c << 2]) = *(const float4*)(queue + ((size_t)(qbase + r) << 7) + (c << 2));
  }
  const _Float16* tvrow = tv + (size_t)tile * NP;
#pragma unroll
  for (int j = 0; j < 4; ++j) {
    int p0 = j * 2048 + t * 8;
    half8 tvv = *(const half8*)(tvrow + p0);
    uint4 u0 = *(const uint4*)(rmu + p0);
    uint4 u1 = *(const uint4*)(rmu + p0 + 4);
    unsigned uu[8] = {u0.x, u0.y, u0.z, u0.w, u1.x, u1.y, u1.z, u1.w};
#pragma unroll
    for (int k = 0; k < 8; ++k) {
      if ((float)tvv[k] >= unpackf(uu[k]) - W_WIN) {
        int pos = atomicAdd(&cnt, 1);
        cand[pos] = (unsigned short)(p0 + k);
      }
    }
  }
  __syncthreads();
  int n = cnt;
  int w = t >> 6, l = t & 63, hl = l >> 5, ll = l & 31;
  for (int ci = w * 2 + hl; ci < n; ci += 8) {
    int p = cand[ci];
    const float* prow = (p < B_N) ? (in1 + ((size_t)p << 7)) : (in2 + ((size_t)(p - B_N) << 7));
    float d = 0.f;
#pragma unroll
    for (int k = 0; k < 32; ++k) {
      float4 a = *(const float4*)(prow + (k << 2));
      float4 b = *(const float4*)(&Qs[ll][k << 2]);
      d = fmaf(a.x, b.x, d);
      d = fmaf(a.y, b.y, d);
      d = fmaf(a.z, b.z, d);
      d = fmaf(a.w, b.w, d);
    }
    int idx = qbase + ll;
#pragma unroll
    for (int m = 1; m < 32; m <<= 1) {
      float ov = __shfl_xor(d, m);
      int oi = __shfl_xor(idx, m);
      if (ov > d || (ov == d && oi < idx)) {
        d = ov;
        idx = oi;
      }
    }
    if (ll == 0) {
      unsigned long long key = ((unsigned long long)packf(d) << 32) | (unsigned)(~idx);
      atomicMax(keys + p, key);
    }
  }
}

// ---- gather: Nh = fp16(queue[idx]); diag = dot(nn, p_other) exact fp32 ----
__global__ __launch_bounds__(256) void k_gather(const float* __restrict__ queue,
                                                const float* __restrict__ in1,
                                                const float* __restrict__ in2,
                                                const unsigned long long* __restrict__ keys,
                                                _Float16* __restrict__ Nh,
                                                float* __restrict__ diag) {
  int t = threadIdx.x, w = t >> 6, l = t & 63;
  int g = blockIdx.x * 4 + w;  // 0..8191
  int view = g >> 12, row = g & (B_N - 1);
  unsigned long long key = keys[g];
  int qidx = (int)(~(unsigned)(key & 0xffffffffull));
  const float* q = queue + (size_t)qidx * D_N;
  float2 qv = *(const float2*)(q + 2 * l);
  *(fp16x2*)(Nh + (size_t)g * D_N + 2 * l) = __builtin_amdgcn_cvt_pkrtz(qv.x, qv.y);
  const float* oth = (view ? in1 : in2) + (size_t)row * D_N;
  float2 ov = *(const float2*)(oth + 2 * l);
  float ss = fmaf(ov.x, ov.x, ov.y * ov.y);
  float d = fmaf(qv.x, ov.x, qv.y * ov.y);
#pragma unroll
  for (int m = 1; m < 64; m <<= 1) {
    ss += __shfl_xor(ss, m);
    d += __shfl_xor(d, m);
  }
  if (l == 0) diag[g] = d / sqrtf(ss);
}

// ---- loss GEMM: 2x2 waves, 128 A-rows x 128 B-cols per block, B staged
//      (dbuf + swizzle); fixed-shift LSE partials over 1024-col chunks ----
__global__ __launch_bounds__(256, 2) void k_loss(const _Float16* __restrict__ Ph,
                                                 const _Float16* __restrict__ Nh,
                                                 float* __restrict__ Spart) {
  __shared__ _Float16 sm[2][16384];
  __shared__ float sred[2][2][64];
  int rb = blockIdx.x;     // 0..127
  int chunk = blockIdx.y;  // 0..3
  int pair = rb >> 5, rowblk = rb & 31;
  const size_t BDh = (size_t)B_N * D_N;
  const _Float16* A = (pair == 0) ? Nh : (pair == 1) ? (Ph + BDh) : (pair == 2) ? (Nh + BDh) : Ph;
  const _Float16* Bm = (pair == 0) ? (Ph + BDh) : (pair == 1) ? Nh : (pair == 2) ? Ph : (Nh + BDh);
  int t = threadIdx.x, l = t & 63, w = t >> 6;
  int wr = w >> 1, wc = w & 1, l15 = l & 15, l4 = l >> 4;
  half8 Af[4][4];
  const _Float16* ab = A + (size_t)(rowblk * 128 + wr * 64 + l15) * D_N + l4 * 8;
#pragma unroll
  for (int ti = 0; ti < 4; ++ti)
#pragma unroll
    for (int ks = 0; ks < 4; ++ks)
      Af[ti][ks] = *(const half8*)(ab + (size_t)ti * 16 * D_N + ks * 32);
  float S[16];
#pragma unroll
  for (int i = 0; i < 16; ++i) S[i] = 0.f;
  const size_t crow0 = (size_t)chunk * 1024;
  STAGE128(Bm, crow0, 0)
#pragma unroll 1
  for (int ct = 0; ct < 8; ++ct) {
    int cur = ct & 1;
    __syncthreads();
    if (ct < 7) STAGE128(Bm, crow0 + (ct + 1) * 128, cur ^ 1)
    const char* bbp = (const char*)(&sm[cur][0]);
    f32x4 acc[4][4];
#pragma unroll
    for (int i = 0; i < 4; ++i)
#pragma unroll
      for (int j = 0; j < 4; ++j) acc[i][j] = (f32x4){0.f, 0.f, 0.f, 0.f};
#pragma unroll
    for (int ks = 0; ks < 4; ++ks) {
      half8 Bf[4];
#pragma unroll
      for (int tj = 0; tj < 4; ++tj) {
        int bloc = wc * 64 + tj * 16 + l15;
        int byteo = bloc * 256 + ((((ks << 2) + l4) ^ (bloc & 7)) << 4);
        Bf[tj] = *(const half8*)(bbp + byteo);
      }
#pragma unroll
      for (int ti = 0; ti < 4; ++ti)
#pragma unroll
        for (int tj = 0; tj < 4; ++tj)
          acc[ti][tj] =
              __builtin_amdgcn_mfma_f32_16x16x32_f16(Af[ti][ks], Bf[tj], acc[ti][tj], 0, 0, 0);
    }
#pragma unroll
    for (int ti = 0; ti < 4; ++ti)
#pragma unroll
      for (int r = 0; r < 4; ++r) {
        float e = 0.f;
#pragma unroll
        for (int tj = 0; tj < 4; ++tj) e += exp2f(fmaf(acc[ti][tj][r], C1F, -C2F));
        S[ti * 4 + r] += e;
      }
  }
#pragma unroll
  for (int i = 0; i < 16; ++i) {
#pragma unroll
    for (int m = 1; m < 16; m <<= 1) S[i] += __shfl_xor(S[i], m);
  }
  __syncthreads();
  if (l15 == 0) {
#pragma unroll
    for (int ti = 0; ti < 4; ++ti)
#pragma unroll
      for (int r = 0; r < 4; ++r) sred[wr][wc][ti * 16 + l4 * 4 + r] = S[ti * 4 + r];
  }
  __syncthreads();
  if (t < 128) {
    int wrr = t >> 6, rl = t & 63;
    float s = sred[wrr][0][rl] + sred[wrr][1][rl];
    int row = pair * B_N + rowblk * 128 + wrr * 64 + rl;
    Spart[(size_t)row * 4 + chunk] = s;
  }
}

__global__ __launch_bounds__(256) void k_merge(const float* __restrict__ Spart,
                                               const float* __restrict__ diag,
                                               float* __restrict__ out) {
  int row = blockIdx.x * 256 + threadIdx.x;  // 0..16383
  const float* sp = Spart + (size_t)row * 4;
  float s = sp[0] + sp[1] + sp[2] + sp[3];
  int pair = row >> 12, r = row & (B_N - 1);
  float dg = diag[(pair >> 1) * B_N + r];
  out[row] = logf(s) + 16.0f - INV_T * dg;
}

extern "C" void kernel_launch(void* const* d_in, const int* in_sizes, int n_in,
                              void* d_out, int out_size, void* d_ws, size_t ws_size,
                              hipStream_t stream) {
  const float* in1 = (const float*)d_in[0];
  const float* in2 = (const float*)d_in[1];
  const float* queue = (const float*)d_in[2];
  float* out = (float*)d_out;
  char* ws = (char*)d_ws;
  _Float16* Ph = (_Float16*)(ws + OFF_PH);
  _Float16* Qhh = (_Float16*)(ws + OFF_QH);
  _Float16* Nh = (_Float16*)(ws + OFF_NH);
  _Float16* TV = (_Float16*)(ws + OFF_TV);
  unsigned* RMU = (unsigned*)(ws + OFF_RMU);
  unsigned long long* KEY = (unsigned long long*)(ws + OFF_KEY);
  float* DG = (float*)(ws + OFF_DG);
  float* SP = (float*)(ws + OFF_SP);

  hipLaunchKernelGGL(k_prep, dim3(4096), dim3(256), 0, stream, in1, in2, queue, Ph, Qhh, KEY, RMU);
  hipLaunchKernelGGL(k_nn, dim3(1024), dim3(256), 0, stream, Qhh, Ph, TV, RMU);
  hipLaunchKernelGGL(k_rescore, dim3(512, 2), dim3(256), 0, stream, queue, in1, in2, TV, RMU, KEY);
  hipLaunchKernelGGL(k_gather, dim3(2048), dim3(256), 0, stream, queue, in1, in2, KEY, Nh, DG);
  hipLaunchKernelGGL(k_loss, dim3(128, 4), dim3(256), 0, stream, Ph, Nh, SP);
  hipLaunchKernelGGL(k_merge, dim3(64), dim3(256), 0, stream, SP, DG, out);
}